// Round 15
// baseline (578.402 us; speedup 1.0000x reference)
//
#include <hip/hip_runtime.h>

// Muskingum-Cunge routing on a full binary tree (heap layout), depth 13.
// N = 8191 reaches, T = 2048 timesteps. Outlet = node 0.
// Round 15: two-step-ahead speculation (R9 skeleton, zero trans on-path).
//   Calibration (R9 vs R14): dep VALU ~7cyc, HW trans dependent-use ~85cyc;
//   R9 = 3 serial trans/step = 395cyc. Fix: at step k issue the EXACT trans
//   pack (log2,2xexp2,2xrcp ~275cyc) for step k+2 from a 2-step prediction
//   (frozen step-(k-1) coefficients); slack = 2 steps. On-path: d=Qr*Rh-1
//   (~1e-2, clamp +-0.4), deg-4 Taylor for Qr^em/Qr^eme, 2 Newton for 1/den
//   -> ~23 dep fmas ~170cyc/step. Packs in 3-slot k%3 arrays (full unroll).
//   Batch head: exact packs for steps 0,1. Else IDENTICAL to R9.
// Fallback: single-WG kernel (round-1 structure, verified) if ws too small.

#define NN 8191
#define TT 2048
#define FBATCH 32
#define NBLK 39
#define BTHREADS 256

#define FLAGS_FOFF 16773120ull            // float offset of flags (unused L0 buf slot)
#define REQ_BYTES  67106816ull            // proven available in rounds 2-14
#define FLAG_STRIDE 16                    // u32 stride between (block,wave) flags

#if __has_builtin(__builtin_amdgcn_exp2f)
__device__ __forceinline__ float fexp2(float x) { return __builtin_amdgcn_exp2f(x); }
#else
__device__ __forceinline__ float fexp2(float x) { return exp2f(x); }
#endif
#if __has_builtin(__builtin_amdgcn_logf)
__device__ __forceinline__ float flog2(float x) { return __builtin_amdgcn_logf(x); }
#else
__device__ __forceinline__ float flog2(float x) { return log2f(x); }
#endif
#if __has_builtin(__builtin_amdgcn_rcpf)
__device__ __forceinline__ float frcp(float x) { return __builtin_amdgcn_rcpf(x); }
#else
__device__ __forceinline__ float frcp(float x) { return 1.0f / x; }
#endif

// ---------------- stage tables (39 blocks) ----------------
__constant__ int g_level[NBLK] = {
    12,12,12,12,12,12,12,12,12,12,12,12,12,12,12,12,
    11,11,11,11,11,11,11,11,
    10,10,10,10,
    9,9,
    8,7,6,5,4,3,2,1,0};
__constant__ int g_cnt[NBLK] = {
    256,256,256,256,256,256,256,256,256,256,256,256,256,256,256,256,
    256,256,256,256,256,256,256,256,
    256,256,256,256,
    256,256,
    256,128,64,32,16,8,4,2,1};
// first block id of each level (level 0..12)
__constant__ int g_first[13] = {38,37,36,35,34,33,32,31,30,28,24,16,0};
// float offset of level-l output buffer inside ws (levels 0..12; level 0 unused)
__constant__ unsigned long long g_off[13] = {
    16773120ull, 16769024ull, 16760832ull, 16744448ull, 16711680ull,
    16646144ull, 16515072ull, 16252928ull, 15728640ull, 14680064ull,
    12582912ull, 8388608ull, 0ull};

__device__ __forceinline__ void waitflags(const unsigned int* fa, const unsigned int* fb,
                                          unsigned int target)
{
    while (true) {
        unsigned int a = __hip_atomic_load(fa, __ATOMIC_RELAXED, __HIP_MEMORY_SCOPE_AGENT);
        unsigned int b = fb ? __hip_atomic_load(fb, __ATOMIC_RELAXED, __HIP_MEMORY_SCOPE_AGENT)
                            : a;
        if (a >= target && b >= target) break;
        __builtin_amdgcn_s_sleep(1);
    }
    // Keep subsequent coherent loads from being hoisted above the poll.
    __builtin_amdgcn_sched_barrier(0);
    asm volatile("" ::: "memory");
}

__global__ void zero_flags(unsigned int* flags)
{
    for (int i = threadIdx.x; i < NBLK * 4 * FLAG_STRIDE; i += 256) flags[i] = 0;
}

__global__ __launch_bounds__(BTHREADS, 1)
void pipe_kernel(const float* __restrict__ lat,
                 const float* __restrict__ nman,
                 const float* __restrict__ len,
                 const float* __restrict__ slp,
                 const float* __restrict__ wcf,
                 const float* __restrict__ wex,
                 const float* __restrict__ dcf,
                 const float* __restrict__ dex,
                 const int*   __restrict__ dtp,
                 float*       __restrict__ out,
                 float*       __restrict__ ws)
{
    const int bid = blockIdx.x;
    const int tid = threadIdx.x;
    const int lvl = g_level[bid];
    const int cnt = g_cnt[bid];
    const int W   = tid >> 6;            // wave id within block
    const int wn  = cnt - W * 64;        // active lanes in this wave
    if (wn <= 0) return;                 // shed fully-inactive waves

    const bool active = (tid < cnt);
    const int B = bid - g_first[lvl];                  // block index within level
    const int m = B * 256 + (active ? tid : 0);        // level-local node index
    const int node = ((1 << lvl) - 1) + m;             // heap index
    const int wbase = B * 256 + W * 64;                // wave's first level-local node

    unsigned int* flags = (unsigned int*)(ws + FLAGS_FOFF);
    unsigned int* myflag = flags + ((size_t)bid * 4 + W) * FLAG_STRIDE;

    // producer-wave flags covering this wave's children (round-5, verified)
    const bool haschild = (lvl < 12);
    const unsigned int* fa = nullptr;
    const unsigned int* fb = nullptr;
    if (haschild) {
        const int Fp = g_first[lvl + 1];
        const int nw = wn < 64 ? wn : 64;
        const int p0 = (2 * wbase) >> 6;
        const int p1 = (2 * wbase + 2 * nw - 1) >> 6;
        fa = flags + ((size_t)(Fp + (p0 >> 2)) * 4 + (p0 & 3)) * FLAG_STRIDE;
        fb = (p1 != p0)
           ? flags + ((size_t)(Fp + (p1 >> 2)) * 4 + (p1 & 3)) * FLAG_STRIDE
           : nullptr;
    }

    const int myW = 1 << lvl;
    const int childW = 1 << (lvl + 1);
    float* myBuf = ws + g_off[lvl];
    const unsigned long long* childBuf =
        haschild ? (const unsigned long long*)(ws + g_off[lvl + 1]) : nullptr;

    const float dtf = (float)dtp[0];

    // per-node derived constants (R11 algebra, absmax-0-verified) + Taylor
    //   e23 = (2/3)de ; em = -e23 ; eme = 1 - we - 2*e23
    //   cc = (5/3) dc^(2/3) sqrt(S)/n ; tkc = 2L/cc
    //   p1c = 0.5*tkc ; p2c = (0.5/(S L wc cc))*tkc
    //   c2e..c4e / c2m..c4m: binomial coeffs for (1+d)^em, (1+d)^eme
    float em, eme, tkc, p1c, p2c, c2e, c3e, c4e, c2m, c3m, c4m;
    float Iold = 0.0f, Oold = 0.0f;
    {
        float n = nman[node], L = len[node], S = slp[node];
        float wc = wcf[node], we = wex[node], dc = dcf[node], de = dex[node];
        float dc23 = fexp2(0.6666667f * flog2(dc));
        float cc = 1.6666667f * dc23 * sqrtf(S) * frcp(n);
        float e23 = 0.6666667f * de;
        em  = -e23;
        eme = 1.0f - we - 2.0f * e23;
        tkc = 2.0f * L * frcp(cc);
        float k1 = 0.5f * frcp(S * L * wc * cc);
        p1c = 0.5f * tkc;
        p2c = k1 * tkc;
        c2e = 0.5f * em * (em - 1.0f);
        c3e = c2e * (em - 2.0f) * 0.33333333f;
        c4e = c3e * (em - 3.0f) * 0.25f;
        c2m = 0.5f * eme * (eme - 1.0f);
        c3m = c2m * (eme - 2.0f) * 0.33333333f;
        c4m = c3m * (eme - 3.0f) * 0.25f;
    }

    float la[FBATCH];
    unsigned long long cv[FBATCH];
    float Inw[FBATCH];

    // speculation state: 3-slot prediction packs (statically indexed via k%3)
    float pR[3], pE1[3], pE12[3], pr[3];
    float twoK_s = 0.0f, A_s = 0.0f, r_s = 0.0f;   // frozen coeffs (stash)

// exact pack from Qh into slot S (trans ops; consumed 2 steps later)
#define PACKCALC(S, QH)                                                        \
    {                                                                          \
        float lgh_ = flog2(QH);                                                \
        pE1[S]  = fexp2(em * lgh_);                                            \
        pE12[S] = fexp2(eme * lgh_);                                           \
        pR[S]   = frcp(QH);                                                    \
        float Ah_ = fmaxf(fmaf(-p2c, pE12[S], p1c * pE1[S]), 0.0f);            \
        pr[S]   = frcp(fmaf(tkc, pE1[S], dtf) - Ah_);                          \
    }

    for (int t0 = 0; t0 < TT; t0 += FBATCH) {
        // ---- lat burst (flag-independent): latency overlaps the poll below.
        if (active) {
#pragma unroll
            for (int k = 0; k < FBATCH; ++k) {
                const float* lp = lat + (size_t)(t0 + k) * NN + node;
                asm volatile("global_load_dword %0, %1, off"
                             : "=v"(la[k]) : "v"(lp));
            }
        }

        if (haschild) waitflags(fa, fb, (unsigned int)(t0 + FBATCH));

        // ---- child burst: 32 coherent 8B loads (sc0 sc1 -> serviced at IF$).
        if (haschild && active) {
#pragma unroll
            for (int k = 0; k < FBATCH; ++k) {
                const unsigned long long* cp =
                    childBuf + (((size_t)(t0 + k) * childW) >> 1) + m;
                asm volatile("global_load_dwordx2 %0, %1, off sc0 sc1"
                             : "=v"(cv[k]) : "v"(cp));
            }
        }

        // ONE wait for the whole burst, then pin program order (rule #18).
        asm volatile("s_waitcnt vmcnt(0)" ::: "memory");
        __builtin_amdgcn_sched_barrier(0);

        if (active) {
            // ---- precompute inflows for the batch (off-path, parallel)
#pragma unroll
            for (int k = 0; k < FBATCH; ++k) {
                float ch = 0.0f;
                if (haschild) {
                    float c0 = __uint_as_float((unsigned int)(cv[k] & 0xffffffffull));
                    float c1 = __uint_as_float((unsigned int)(cv[k] >> 32));
                    ch = c0 + c1;
                }
                Inw[k] = la[k] + ch;
            }

            // ---- batch head: exact pack for step 0; predicted pack for step 1
            {
                float Qh0 = fmaxf(0.5f * (Inw[0] + Oold), 1e-3f);
                PACKCALC(0, Qh0);
                twoK_s = tkc * pE1[0];
                A_s = fmaxf(fmaf(-p2c, pE12[0], p1c * pE1[0]), 0.0f);
                r_s = pr[0];
                float s1h = (Inw[0] + Iold) - Oold;
                float s2h = fmaf(-2.0f, Inw[0], s1h);
                float Oh = fmaxf(fmaf(A_s, s2h, fmaf(twoK_s, Oold, dtf * s1h)) * r_s, 0.0f);
                float Qh1 = fmaxf(0.5f * (Inw[1] + Oh), 1e-3f);
                PACKCALC(1, Qh1);
            }

            // ---- serial chain: zero transcendentals on the dependent path
#pragma unroll
            for (int k = 0; k < FBATCH; ++k) {
                float s1 = (Inw[k] + Iold) - Oold;
                float s2 = fmaf(-2.0f, Inw[k], s1);

                // speculative pack for step k+2 (off-path; 2-step slack)
                if (k < FBATCH - 2) {
                    float Oh0 = fmaxf(fmaf(A_s, s2, fmaf(twoK_s, Oold, dtf * s1)) * r_s, 0.0f);
                    float sh1 = (Inw[k + 1] + Inw[k]) - Oh0;
                    float sh2 = fmaf(-2.0f, Inw[k + 1], sh1);
                    float Oh1 = fmaxf(fmaf(A_s, sh2, fmaf(twoK_s, Oh0, dtf * sh1)) * r_s, 0.0f);
                    float Qh = fmaxf(0.5f * (Inw[k + 2] + Oh1), 1e-3f);
                    PACKCALC((k + 2) % 3, Qh);
                }

                // corrected on-path step (pack slot k%3)
                const int c = k % 3;
                float Qr = fmaxf(0.5f * (Inw[k] + Oold), 1e-3f);
                float d = fmaf(Qr, pR[c], -1.0f);
                d = fminf(fmaxf(d, -0.4f), 0.4f);
                float f1 = fmaf(fmaf(fmaf(fmaf(c4e, d, c3e), d, c2e), d, em), d, 1.0f);
                float f2 = fmaf(fmaf(fmaf(fmaf(c4m, d, c3m), d, c2m), d, eme), d, 1.0f);
                float E1 = pE1[c] * f1;
                float E12 = pE12[c] * f2;
                float twoK = tkc * E1;
                float A = fmaxf(fmaf(-p2c, E12, p1c * E1), 0.0f);
                float den = (twoK + dtf) - A;
                float rr = pr[c];
                rr = rr * fmaf(-den, rr, 2.0f);
                rr = rr * fmaf(-den, rr, 2.0f);
                float num = fmaf(A, s2, fmaf(twoK, Oold, dtf * s1));
                float O = fmaxf(num * rr, 0.0f);
                twoK_s = twoK; A_s = A; r_s = rr;
                Iold = Inw[k]; Oold = O;
                if (lvl > 0)
                    __hip_atomic_store(myBuf + (size_t)(t0 + k) * myW + m, O,
                                       __ATOMIC_RELAXED, __HIP_MEMORY_SCOPE_AGENT);
                else
                    out[t0 + k] = O;
            }
        }

        if (lvl > 0) {
            // per-wave publish: stores acked at coherency point, then flag.
            asm volatile("s_waitcnt vmcnt(0)" ::: "memory");
            if ((tid & 63) == 0)
                __hip_atomic_store(myflag, (unsigned int)(t0 + FBATCH),
                                   __ATOMIC_RELAXED, __HIP_MEMORY_SCOPE_AGENT);
        }
    }
#undef PACKCALC
}

// ---------------- fallback: single-WG kernel (round-1 structure, verified) ----
#define NTHREADS 1024
__device__ __forceinline__ float mc_update_fb(float Inew, float Iold, float Oold,
                                              float em, float tkc, float ex, float k1,
                                              float dtf)
{
    float Qr = fmaxf(0.5f * (Inew + Oold), 1e-3f);
    float lg = flog2(Qr);
    float twoK = tkc * fexp2(em * lg);
    float X = fmaxf(0.5f - k1 * fexp2(ex * lg), 0.0f);
    float A = twoK * X;
    float B = twoK - A;
    float r = frcp(B + dtf);
    float C1 = (dtf - A) * r;
    float C2 = (dtf + A) * r;
    float C3 = (B - dtf) * r;
    return fmaxf(C1 * Inew + C2 * Iold + C3 * Oold, 0.0f);
}

__global__ __launch_bounds__(NTHREADS)
void route_kernel(const float* __restrict__ lat,
                  const float* __restrict__ nman,
                  const float* __restrict__ len,
                  const float* __restrict__ slp,
                  const float* __restrict__ wcf,
                  const float* __restrict__ wex,
                  const float* __restrict__ dcf,
                  const float* __restrict__ dex,
                  const int*   __restrict__ dtp,
                  float*       __restrict__ out)
{
    __shared__ float Osh[NN];
    const int tid = threadIdx.x;
    const float dtf = (float)dtp[0];

    int nodes[8];
    nodes[0] = 4095 + tid;
    nodes[1] = 5119 + tid;
    nodes[2] = 6143 + tid;
    nodes[3] = 7167 + tid;
    nodes[4] = 2047 + tid;
    nodes[5] = 3071 + tid;
    nodes[6] = 1023 + tid;
    nodes[7] = (tid < 1023) ? tid : 0;

    float em[8], tkc[8], ex[8], k1[8];
    float Ireg[8], Oreg[8];
#pragma unroll
    for (int k = 0; k < 8; ++k) {
        int i = nodes[k];
        float n = nman[i], L = len[i], S = slp[i];
        float wc = wcf[i], we = wex[i], dc = dcf[i], de = dex[i];
        float dc23 = fexp2(0.6666667f * flog2(dc));
        float cc = 1.6666667f * dc23 * sqrtf(S) * frcp(n);
        float e23 = 0.6666667f * de;
        em[k]  = -e23;
        tkc[k] = 2.0f * L * frcp(cc);
        ex[k]  = 1.0f - we - e23;
        k1[k]  = 0.5f * frcp(S * L * wc * cc);
        Ireg[k] = 0.0f; Oreg[k] = 0.0f;
    }
    for (int i = tid; i < NN; i += NTHREADS) Osh[i] = 0.0f;
    __syncthreads();

    for (int t = 0; t < TT; ++t) {
        const float* __restrict__ latt = lat + (size_t)t * NN;
#pragma unroll
        for (int k = 0; k < 4; ++k) {
            int i = nodes[k];
            float Inew = latt[i];
            float O = mc_update_fb(Inew, Ireg[k], Oreg[k], em[k], tkc[k], ex[k], k1[k], dtf);
            Ireg[k] = Inew; Oreg[k] = O; Osh[i] = O;
        }
        __syncthreads();
#pragma unroll
        for (int k = 4; k < 6; ++k) {
            int i = nodes[k];
            float Inew = latt[i] + Osh[2 * i + 1] + Osh[2 * i + 2];
            float O = mc_update_fb(Inew, Ireg[k], Oreg[k], em[k], tkc[k], ex[k], k1[k], dtf);
            Ireg[k] = Inew; Oreg[k] = O; Osh[i] = O;
        }
        __syncthreads();
        {
            int i = nodes[6];
            float Inew = latt[i] + Osh[2 * i + 1] + Osh[2 * i + 2];
            float O = mc_update_fb(Inew, Ireg[6], Oreg[6], em[6], tkc[6], ex[6], k1[6], dtf);
            Ireg[6] = Inew; Oreg[6] = O; Osh[i] = O;
        }
        __syncthreads();
        for (int l = 9; l >= 0; --l) {
            int s = (1 << l) - 1;
            int e = (1 << (l + 1)) - 1;
            if (tid >= s && tid < e) {
                int i = tid;
                float Inew = latt[i] + Osh[2 * i + 1] + Osh[2 * i + 2];
                float O = mc_update_fb(Inew, Ireg[7], Oreg[7], em[7], tkc[7], ex[7], k1[7], dtf);
                Ireg[7] = Inew; Oreg[7] = O; Osh[i] = O;
            }
            __syncthreads();
        }
        if (tid == 0) out[t] = Oreg[7];
    }
}

extern "C" void kernel_launch(void* const* d_in, const int* in_sizes, int n_in,
                              void* d_out, int out_size, void* d_ws, size_t ws_size,
                              hipStream_t stream) {
    const float* lat  = (const float*)d_in[0];
    const float* nman = (const float*)d_in[1];
    const float* len  = (const float*)d_in[2];
    const float* slp  = (const float*)d_in[3];
    const float* wcf  = (const float*)d_in[4];
    const float* wex  = (const float*)d_in[5];
    const float* dcf  = (const float*)d_in[6];
    const float* dex  = (const float*)d_in[7];
    const int*   dtp  = (const int*)d_in[8];
    float* out = (float*)d_out;

    if (ws_size >= REQ_BYTES) {
        float* ws = (float*)d_ws;
        unsigned int* flags = (unsigned int*)(ws + FLAGS_FOFF);
        zero_flags<<<dim3(1), dim3(256), 0, stream>>>(flags);
        pipe_kernel<<<dim3(NBLK), dim3(BTHREADS), 0, stream>>>(
            lat, nman, len, slp, wcf, wex, dcf, dex, dtp, out, ws);
    } else {
        route_kernel<<<dim3(1), dim3(NTHREADS), 0, stream>>>(
            lat, nman, len, slp, wcf, wex, dcf, dex, dtp, out);
    }
}

// Round 17
// 409.145 us; speedup vs baseline: 1.4137x; 1.4137x over previous
//
#include <hip/hip_runtime.h>

// Muskingum-Cunge routing on a full binary tree (heap layout), depth 13.
// N = 8191 reaches, T = 2048 timesteps. Outlet = node 0.
// Round 17: R9 skeleton (best, 404us) + RAW hardware transcendentals.
//   Key realization: R1-R12's absmax == 0.0 (bitwise match to the JAX ref
//   through 26M chained pow/exp evaluations) proves the flog2/fexp2 wrappers
//   compiled to PRECISE SOFTWARE routines, not v_log_f32/v_exp_f32. The
//   measured ~90cyc per "transcendental" was a software sequence. Replace the
//   three chain trans with inline-asm v_log_f32/v_exp_f32/v_rcp_f32
//   (non-volatile: pure, schedulable, HW-interlocked). Chain ~390 -> ~180cyc.
//   Everything else byte-identical to R9.
// Fallback: single-WG kernel (round-1 structure, verified) if ws too small.

#define NN 8191
#define TT 2048
#define FBATCH 32
#define NBLK 39
#define BTHREADS 256

#define FLAGS_FOFF 16773120ull            // float offset of flags (unused L0 buf slot)
#define REQ_BYTES  67106816ull            // proven available in rounds 2-16
#define FLAG_STRIDE 16                    // u32 stride between (block,wave) flags

// precise (software) versions — used in the fallback kernel only
#if __has_builtin(__builtin_amdgcn_exp2f)
__device__ __forceinline__ float fexp2(float x) { return __builtin_amdgcn_exp2f(x); }
#else
__device__ __forceinline__ float fexp2(float x) { return exp2f(x); }
#endif
#if __has_builtin(__builtin_amdgcn_logf)
__device__ __forceinline__ float flog2(float x) { return __builtin_amdgcn_logf(x); }
#else
__device__ __forceinline__ float flog2(float x) { return log2f(x); }
#endif
#if __has_builtin(__builtin_amdgcn_rcpf)
__device__ __forceinline__ float frcp(float x) { return __builtin_amdgcn_rcpf(x); }
#else
__device__ __forceinline__ float frcp(float x) { return 1.0f / x; }
#endif

// RAW hardware transcendentals (guaranteed single-instruction).
__device__ __forceinline__ float hlog2(float x) {
    float r; asm("v_log_f32 %0, %1" : "=v"(r) : "v"(x)); return r;
}
__device__ __forceinline__ float hexp2(float x) {
    float r; asm("v_exp_f32 %0, %1" : "=v"(r) : "v"(x)); return r;
}
__device__ __forceinline__ float hrcp(float x) {
    float r; asm("v_rcp_f32 %0, %1" : "=v"(r) : "v"(x)); return r;
}

// ---------------- stage tables (39 blocks) ----------------
__constant__ int g_level[NBLK] = {
    12,12,12,12,12,12,12,12,12,12,12,12,12,12,12,12,
    11,11,11,11,11,11,11,11,
    10,10,10,10,
    9,9,
    8,7,6,5,4,3,2,1,0};
__constant__ int g_cnt[NBLK] = {
    256,256,256,256,256,256,256,256,256,256,256,256,256,256,256,256,
    256,256,256,256,256,256,256,256,
    256,256,256,256,
    256,256,
    256,128,64,32,16,8,4,2,1};
// first block id of each level (level 0..12)
__constant__ int g_first[13] = {38,37,36,35,34,33,32,31,30,28,24,16,0};
// float offset of level-l output buffer inside ws (levels 0..12; level 0 unused)
__constant__ unsigned long long g_off[13] = {
    16773120ull, 16769024ull, 16760832ull, 16744448ull, 16711680ull,
    16646144ull, 16515072ull, 16252928ull, 15728640ull, 14680064ull,
    12582912ull, 8388608ull, 0ull};

__device__ __forceinline__ void waitflags(const unsigned int* fa, const unsigned int* fb,
                                          unsigned int target)
{
    while (true) {
        unsigned int a = __hip_atomic_load(fa, __ATOMIC_RELAXED, __HIP_MEMORY_SCOPE_AGENT);
        unsigned int b = fb ? __hip_atomic_load(fb, __ATOMIC_RELAXED, __HIP_MEMORY_SCOPE_AGENT)
                            : a;
        if (a >= target && b >= target) break;
        __builtin_amdgcn_s_sleep(1);
    }
    // Keep subsequent coherent loads from being hoisted above the poll.
    __builtin_amdgcn_sched_barrier(0);
    asm volatile("" ::: "memory");
}

__global__ void zero_flags(unsigned int* flags)
{
    for (int i = threadIdx.x; i < NBLK * 4 * FLAG_STRIDE; i += 256) flags[i] = 0;
}

__global__ __launch_bounds__(BTHREADS, 1)
void pipe_kernel(const float* __restrict__ lat,
                 const float* __restrict__ nman,
                 const float* __restrict__ len,
                 const float* __restrict__ slp,
                 const float* __restrict__ wcf,
                 const float* __restrict__ wex,
                 const float* __restrict__ dcf,
                 const float* __restrict__ dex,
                 const int*   __restrict__ dtp,
                 float*       __restrict__ out,
                 float*       __restrict__ ws)
{
    const int bid = blockIdx.x;
    const int tid = threadIdx.x;
    const int lvl = g_level[bid];
    const int cnt = g_cnt[bid];
    const int W   = tid >> 6;            // wave id within block
    const int wn  = cnt - W * 64;        // active lanes in this wave
    if (wn <= 0) return;                 // shed fully-inactive waves

    const bool active = (tid < cnt);
    const int B = bid - g_first[lvl];                  // block index within level
    const int m = B * 256 + (active ? tid : 0);        // level-local node index
    const int node = ((1 << lvl) - 1) + m;             // heap index
    const int wbase = B * 256 + W * 64;                // wave's first level-local node

    unsigned int* flags = (unsigned int*)(ws + FLAGS_FOFF);
    unsigned int* myflag = flags + ((size_t)bid * 4 + W) * FLAG_STRIDE;

    // producer-wave flags covering this wave's children (round-5, verified)
    const bool haschild = (lvl < 12);
    const unsigned int* fa = nullptr;
    const unsigned int* fb = nullptr;
    if (haschild) {
        const int Fp = g_first[lvl + 1];
        const int nw = wn < 64 ? wn : 64;
        const int p0 = (2 * wbase) >> 6;
        const int p1 = (2 * wbase + 2 * nw - 1) >> 6;
        fa = flags + ((size_t)(Fp + (p0 >> 2)) * 4 + (p0 & 3)) * FLAG_STRIDE;
        fb = (p1 != p0)
           ? flags + ((size_t)(Fp + (p1 >> 2)) * 4 + (p1 & 3)) * FLAG_STRIDE
           : nullptr;
    }

    const int myW = 1 << lvl;
    const int childW = 1 << (lvl + 1);
    float* myBuf = ws + g_off[lvl];
    const unsigned long long* childBuf =
        haschild ? (const unsigned long long*)(ws + g_off[lvl + 1]) : nullptr;

    const float dtf = (float)dtp[0];

    // per-node derived constants + state (registers, persistent)
    //   em  = -(2/3)de ; tkc = 2L/cc ; ex = 1 - we - (2/3)de ; k1 = 0.5/(S L wc cc)
    float em, tkc, ex, k1;
    float Iold = 0.0f, Oold = 0.0f;
    {
        float n = nman[node], L = len[node], S = slp[node];
        float wc = wcf[node], we = wex[node], dc = dcf[node], de = dex[node];
        float dc23 = hexp2(0.6666667f * hlog2(dc));
        float cc = 1.6666667f * dc23 * sqrtf(S) * hrcp(n);
        float e23 = 0.6666667f * de;
        em  = -e23;
        tkc = 2.0f * L * hrcp(cc);
        ex  = 1.0f - we - e23;
        k1  = 0.5f * hrcp(S * L * wc * cc);
    }

    float la[FBATCH];
    unsigned long long cv[FBATCH];

    for (int t0 = 0; t0 < TT; t0 += FBATCH) {
        // ---- lat burst (flag-independent): latency overlaps the poll below.
        if (active) {
#pragma unroll
            for (int k = 0; k < FBATCH; ++k) {
                const float* lp = lat + (size_t)(t0 + k) * NN + node;
                asm volatile("global_load_dword %0, %1, off"
                             : "=v"(la[k]) : "v"(lp));
            }
        }

        if (haschild) waitflags(fa, fb, (unsigned int)(t0 + FBATCH));

        // ---- child burst: 32 coherent 8B loads (sc0 sc1 -> serviced at IF$).
        if (haschild && active) {
#pragma unroll
            for (int k = 0; k < FBATCH; ++k) {
                const unsigned long long* cp =
                    childBuf + (((size_t)(t0 + k) * childW) >> 1) + m;
                asm volatile("global_load_dwordx2 %0, %1, off sc0 sc1"
                             : "=v"(cv[k]) : "v"(cp));
            }
        }

        // ONE wait for the whole burst, then pin program order (rule #18).
        asm volatile("s_waitcnt vmcnt(0)" ::: "memory");
        __builtin_amdgcn_sched_barrier(0);

        // ---- serial compute chain: RAW hw trans (v_log/v_exp/v_rcp).
        if (active) {
#pragma unroll
            for (int k = 0; k < FBATCH; ++k) {
                float ch = 0.0f;
                if (haschild) {
                    float c0 = __uint_as_float((unsigned int)(cv[k] & 0xffffffffull));
                    float c1 = __uint_as_float((unsigned int)(cv[k] >> 32));
                    ch = c0 + c1;
                }
                float Inew = la[k] + ch;
                float Qr = fmaxf(0.5f * (Inew + Oold), 1e-3f);
                float lg = hlog2(Qr);
                float twoK = tkc * hexp2(em * lg);
                float X = fmaxf(0.5f - k1 * hexp2(ex * lg), 0.0f);
                float A = twoK * X;
                float Bv = twoK - A;
                float r = hrcp(Bv + dtf);
                float num = dtf * (Inew + Iold - Oold) + A * (Iold - Inew) + Bv * Oold;
                float O = fmaxf(num * r, 0.0f);
                Iold = Inew; Oold = O;
                if (lvl > 0)
                    __hip_atomic_store(myBuf + (size_t)(t0 + k) * myW + m, O,
                                       __ATOMIC_RELAXED, __HIP_MEMORY_SCOPE_AGENT);
                else
                    out[t0 + k] = O;
            }
        }

        if (lvl > 0) {
            // per-wave publish: stores acked at coherency point, then flag.
            asm volatile("s_waitcnt vmcnt(0)" ::: "memory");
            if ((tid & 63) == 0)
                __hip_atomic_store(myflag, (unsigned int)(t0 + FBATCH),
                                   __ATOMIC_RELAXED, __HIP_MEMORY_SCOPE_AGENT);
        }
    }
}

// ---------------- fallback: single-WG kernel (round-1 structure, verified) ----
#define NTHREADS 1024
__device__ __forceinline__ float mc_update_fb(float Inew, float Iold, float Oold,
                                              float em, float tkc, float ex, float k1,
                                              float dtf)
{
    float Qr = fmaxf(0.5f * (Inew + Oold), 1e-3f);
    float lg = flog2(Qr);
    float twoK = tkc * fexp2(em * lg);
    float X = fmaxf(0.5f - k1 * fexp2(ex * lg), 0.0f);
    float A = twoK * X;
    float B = twoK - A;
    float r = frcp(B + dtf);
    float C1 = (dtf - A) * r;
    float C2 = (dtf + A) * r;
    float C3 = (B - dtf) * r;
    return fmaxf(C1 * Inew + C2 * Iold + C3 * Oold, 0.0f);
}

__global__ __launch_bounds__(NTHREADS)
void route_kernel(const float* __restrict__ lat,
                  const float* __restrict__ nman,
                  const float* __restrict__ len,
                  const float* __restrict__ slp,
                  const float* __restrict__ wcf,
                  const float* __restrict__ wex,
                  const float* __restrict__ dcf,
                  const float* __restrict__ dex,
                  const int*   __restrict__ dtp,
                  float*       __restrict__ out)
{
    __shared__ float Osh[NN];
    const int tid = threadIdx.x;
    const float dtf = (float)dtp[0];

    int nodes[8];
    nodes[0] = 4095 + tid;
    nodes[1] = 5119 + tid;
    nodes[2] = 6143 + tid;
    nodes[3] = 7167 + tid;
    nodes[4] = 2047 + tid;
    nodes[5] = 3071 + tid;
    nodes[6] = 1023 + tid;
    nodes[7] = (tid < 1023) ? tid : 0;

    float em[8], tkc[8], ex[8], k1[8];
    float Ireg[8], Oreg[8];
#pragma unroll
    for (int k = 0; k < 8; ++k) {
        int i = nodes[k];
        float n = nman[i], L = len[i], S = slp[i];
        float wc = wcf[i], we = wex[i], dc = dcf[i], de = dex[i];
        float dc23 = fexp2(0.6666667f * flog2(dc));
        float cc = 1.6666667f * dc23 * sqrtf(S) * frcp(n);
        float e23 = 0.6666667f * de;
        em[k]  = -e23;
        tkc[k] = 2.0f * L * frcp(cc);
        ex[k]  = 1.0f - we - e23;
        k1[k]  = 0.5f * frcp(S * L * wc * cc);
        Ireg[k] = 0.0f; Oreg[k] = 0.0f;
    }
    for (int i = tid; i < NN; i += NTHREADS) Osh[i] = 0.0f;
    __syncthreads();

    for (int t = 0; t < TT; ++t) {
        const float* __restrict__ latt = lat + (size_t)t * NN;
#pragma unroll
        for (int k = 0; k < 4; ++k) {
            int i = nodes[k];
            float Inew = latt[i];
            float O = mc_update_fb(Inew, Ireg[k], Oreg[k], em[k], tkc[k], ex[k], k1[k], dtf);
            Ireg[k] = Inew; Oreg[k] = O; Osh[i] = O;
        }
        __syncthreads();
#pragma unroll
        for (int k = 4; k < 6; ++k) {
            int i = nodes[k];
            float Inew = latt[i] + Osh[2 * i + 1] + Osh[2 * i + 2];
            float O = mc_update_fb(Inew, Ireg[k], Oreg[k], em[k], tkc[k], ex[k], k1[k], dtf);
            Ireg[k] = Inew; Oreg[k] = O; Osh[i] = O;
        }
        __syncthreads();
        {
            int i = nodes[6];
            float Inew = latt[i] + Osh[2 * i + 1] + Osh[2 * i + 2];
            float O = mc_update_fb(Inew, Ireg[6], Oreg[6], em[6], tkc[6], ex[6], k1[6], dtf);
            Ireg[6] = Inew; Oreg[6] = O; Osh[i] = O;
        }
        __syncthreads();
        for (int l = 9; l >= 0; --l) {
            int s = (1 << l) - 1;
            int e = (1 << (l + 1)) - 1;
            if (tid >= s && tid < e) {
                int i = tid;
                float Inew = latt[i] + Osh[2 * i + 1] + Osh[2 * i + 2];
                float O = mc_update_fb(Inew, Ireg[7], Oreg[7], em[7], tkc[7], ex[7], k1[7], dtf);
                Ireg[7] = Inew; Oreg[7] = O; Osh[i] = O;
            }
            __syncthreads();
        }
        if (tid == 0) out[t] = Oreg[7];
    }
}

extern "C" void kernel_launch(void* const* d_in, const int* in_sizes, int n_in,
                              void* d_out, int out_size, void* d_ws, size_t ws_size,
                              hipStream_t stream) {
    const float* lat  = (const float*)d_in[0];
    const float* nman = (const float*)d_in[1];
    const float* len  = (const float*)d_in[2];
    const float* slp  = (const float*)d_in[3];
    const float* wcf  = (const float*)d_in[4];
    const float* wex  = (const float*)d_in[5];
    const float* dcf  = (const float*)d_in[6];
    const float* dex  = (const float*)d_in[7];
    const int*   dtp  = (const int*)d_in[8];
    float* out = (float*)d_out;

    if (ws_size >= REQ_BYTES) {
        float* ws = (float*)d_ws;
        unsigned int* flags = (unsigned int*)(ws + FLAGS_FOFF);
        zero_flags<<<dim3(1), dim3(256), 0, stream>>>(flags);
        pipe_kernel<<<dim3(NBLK), dim3(BTHREADS), 0, stream>>>(
            lat, nman, len, slp, wcf, wex, dcf, dex, dtp, out, ws);
    } else {
        route_kernel<<<dim3(1), dim3(NTHREADS), 0, stream>>>(
            lat, nman, len, slp, wcf, wex, dcf, dex, dtp, out);
    }
}